// Round 6
// baseline (317.295 us; speedup 1.0000x reference)
//
#include <hip/hip_runtime.h>

typedef _Float16 f16x8 __attribute__((ext_vector_type(8)));
typedef _Float16 f16x4 __attribute__((ext_vector_type(4)));
typedef float f32x4 __attribute__((ext_vector_type(4)));
typedef int   v4i   __attribute__((ext_vector_type(4)));

// Async global->LDS, 16B per lane. LDS dest must be wave-uniform base; HW adds lane*16.
__device__ __forceinline__ void lds_load16(const _Float16* g, _Float16* l) {
    __builtin_amdgcn_global_load_lds(
        (const __attribute__((address_space(1))) void*)g,
        (__attribute__((address_space(3))) void*)l,
        16, 0, 0);
}

// Inline-asm LDS read with compile-time offset. Rule #18: every use is fenced
// by lgkmcnt(0) + sched_barrier(0) before the consuming MFMA.
template <int OFF>
__device__ __forceinline__ f16x8 ldsrO(unsigned a) {
    v4i r;
    if constexpr (OFF == 0)
        asm volatile("ds_read_b128 %0, %1" : "=v"(r) : "v"(a));
    else
        asm volatile("ds_read_b128 %0, %1 offset:%2" : "=v"(r) : "v"(a), "i"(OFF));
    return __builtin_bit_cast(f16x8, r);
}

// ---------------------------------------------------------------------------
// NT GEMM core: C[M,N] = A[M,K]*B[N,K]^T. f16 in, fp32 acc.
// High-TLP old-drain pipeline: tile 128x128, BK=32, 256 thr = 4 waves (2x2),
// wave-tile 64x64, acc[4][4]. TRIPLE-buffered LDS (3 x 16KB = 48KB ->
// 3 blocks/CU, 12 waves/CU). Per K-step kc:
//   { asm ds_read frags from buf kc%3  ->  stage buf (kc+2)%3 (4 gload_lds)
//     -> lgkmcnt(0) -> setprio(1) 16 MFMA setprio(0)
//     -> s_waitcnt vmcnt(4)   [drains stage kc+1, issued ONE FULL ITERATION
//        ago (~1500 cyc) => drain ~free; keeps kc+2's 4 loads in flight]
//     -> raw s_barrier (publishes buf kc+1 for next iter) }.
// Safety: all waves rendezvous at the barrier after reading buf kc and after
// draining their own kc+1 loads; staging targets (kc+2)%3 which no wave can
// still be reading. Never vmcnt(0) in steady state.
//
// LDS swizzle (both-sides, rule #21; R1-measured 0 conflicts): LDS[row][slot]
// = G[row][slot ^ ((row>>1)&3)] (16B slots, 4/row) via pre-swizzled per-lane
// GLOBAL source (linear gload_lds dest) + slot XOR on the read side.
//
// MODE 0: triple projection, z in {0,1,2}:
//   z=0: q  = Xqh@WqT^T + bq[n]   z=1: k = Xkh@WkT^T + bk[n]   (ldc=1024)
//   z=2: vT = WvT@Xvh^T + bv[m]   (ldc=8192)
//   grid (8,64,3) = 1536 blocks = 2.0 exact machine-waves at 3 blocks/CU.
// MODE 3: S~ = exp((q k^T)/32) f16 + atomic f32 row sums; grid (8,32,4).
// MODE 5: out = (S~ @ v)/rowsum f32; grid (8,16,4) = 512 blocks = 2/CU.
// ---------------------------------------------------------------------------
template <int MODE>
__global__ __launch_bounds__(256, 3)
void gemm_core(const _Float16* A0, const _Float16* B0, void* C0, const float* b0,
               const _Float16* A1, const _Float16* B1, void* C1, const float* b1,
               const _Float16* A2, const _Float16* B2, void* C2, const float* b2,
               float* rowsum)
{
    constexpr int K   = (MODE == 5) ? 2048 : 1024;
    constexpr int LDA = (MODE == 5) ? 2048 : 1024;
    constexpr int LDB = (MODE == 5) ? 8192 : 1024;
    constexpr int NT  = K / 32;

    __shared__ __align__(16) _Float16 As[3][128 * 32];
    __shared__ __align__(16) _Float16 Bs[3][128 * 32];

    const int z_ = blockIdx.z;
    const int bx = blockIdx.x, by = blockIdx.y;
    const int t    = threadIdx.x;
    const int w    = t >> 6;
    const int lane = t & 63;
    const int ln   = lane & 15;
    const int kq   = lane >> 4;
    const int wm   = (w & 1) * 64;
    const int wn   = (w >> 1) * 64;

    const _Float16* A;
    const _Float16* B;
    size_t cbase = 0;
    int m0, n0, z = z_;

    if (MODE == 0) {
        // grid (8,64,3); XCD = bx. z0/z1: XCD owns a 1024-row A strip (2MB,
        // fetched once) x all 8 n-tiles; B panel (2MB) L2-resident. z2:
        // XCD owns a 1024-row Xvh strip (B side).
        A = z == 0 ? A0 : z == 1 ? A1 : A2;
        B = z == 0 ? B0 : z == 1 ? B1 : B2;
        if (z == 2) { m0 = (by & 7) * 128; n0 = (bx * 8 + (by >> 3)) * 128; }
        else        { m0 = (bx * 8 + (by >> 3)) * 128; n0 = (by & 7) * 128; }
    } else if (MODE == 3) {
        // grid (8,32,4); XCD = bx: 2 m-tiles (q 512KB) x 16 n (k 4MB) per XCD.
        A = A0 + (size_t)z * 2048 * 1024;      // q slice
        B = B0 + (size_t)z * 2048 * 1024;      // k slice
        cbase = (size_t)z * 2048 * 2048;
        rowsum += z * 2048;
        m0 = (bx * 2 + (by >> 4)) * 128;
        n0 = (by & 15) * 128;
    } else {
        // grid (8,16,4); XCD = bx = n-tile: 128-col vT strip per XCD.
        A = A0 + (size_t)z * 2048 * 2048;      // S~ slice
        B = B0 + (size_t)z * 2048;             // vT col offset
        cbase = (size_t)z * 2048 * 1024;
        rowsum += z * 2048;
        m0 = by * 128;
        n0 = bx * 128;
    }

    // ---- staging (pre-swizzled global source, linear LDS dest) ----
    // thread t: rows r4=t>>2 and r4+64; global 16B-chunk (t&3)^((r4>>1)&3).
    const int r4 = t >> 2;
    const int sc = ((t & 3) ^ ((t >> 3) & 3)) * 8;
    const _Float16* gA = A + (size_t)(m0 + r4) * LDA + sc;
    const _Float16* gB = B + (size_t)(n0 + r4) * LDB + sc;
    _Float16* const lA = &As[0][0] + w * 512;         // + bufE + s*2048
    _Float16* const lB = &Bs[0][0] + w * 512;

    auto stage = [&](unsigned bufE, int kt) {         // bufE: element offset of buf
        lds_load16(gA + kt * 32,                     lA + bufE);
        lds_load16(gA + (size_t)64 * LDA + kt * 32,  lA + bufE + 2048);
        lds_load16(gB + kt * 32,                     lB + bufE);
        lds_load16(gB + (size_t)64 * LDB + kt * 32,  lB + bufE + 2048);
    };

    // ---- read-side byte addresses (row*64B + swizzled 16B slot) ----
    const int sk = (kq ^ ((ln >> 1) & 3)) * 16;
    const unsigned uA0 = (unsigned)(uintptr_t)(__attribute__((address_space(3))) _Float16*)&As[0][0];
    const unsigned uB0 = (unsigned)(uintptr_t)(__attribute__((address_space(3))) _Float16*)&Bs[0][0];
    const unsigned vAbase = uA0 + (wm + ln) * 64 + sk;
    const unsigned vBbase = uB0 + (wn + ln) * 64 + sk;

    f32x4 acc[4][4] = {};

    // prologue: stage kt0->buf0, kt1->buf1; drain kt0 (keep kt1 in flight)
    stage(0, 0);
    stage(4096, 1);
    asm volatile("s_waitcnt vmcnt(4)" ::: "memory");
    __builtin_amdgcn_s_barrier();
    __builtin_amdgcn_sched_barrier(0);

    unsigned offR = 0;        // read-buf byte offset:  0, 8192, 16384, ...
    unsigned offW = 8192;     // stage-buf elem offset: (kc+2)%3 * 4096

    for (int kc = 0; kc < NT; ++kc) {
        // ---- fragment reads from buf kc%3 ----
        const unsigned aA = vAbase + offR;
        const unsigned aB = vBbase + offR;
        f16x8 af[4], bf[4];
        af[0] = ldsrO<0>(aA);    af[1] = ldsrO<1024>(aA);
        af[2] = ldsrO<2048>(aA); af[3] = ldsrO<3072>(aA);
        bf[0] = ldsrO<0>(aB);    bf[1] = ldsrO<1024>(aB);
        bf[2] = ldsrO<2048>(aB); bf[3] = ldsrO<3072>(aB);

        // ---- stage kc+2 into buf (kc+2)%3 (no wave can be reading it) ----
        const bool pf = (kc + 2 < NT);
        if (pf) stage(offW, kc + 2);

        asm volatile("s_waitcnt lgkmcnt(0)" ::: "memory");
        __builtin_amdgcn_sched_barrier(0);
        __builtin_amdgcn_s_setprio(1);
#pragma unroll
        for (int i = 0; i < 4; ++i)
#pragma unroll
            for (int j = 0; j < 4; ++j)
                acc[i][j] = __builtin_amdgcn_mfma_f32_16x16x32_f16(af[i], bf[j], acc[i][j], 0, 0, 0);
        __builtin_amdgcn_s_setprio(0);
        __builtin_amdgcn_sched_barrier(0);

        // ---- old-drain: wait for stage kc+1 (issued a full iter ago),
        //      keep kc+2's 4 loads in flight; publish via barrier ----
        if (pf) asm volatile("s_waitcnt vmcnt(4)" ::: "memory");
        else    asm volatile("s_waitcnt vmcnt(0)" ::: "memory");
        __builtin_amdgcn_s_barrier();
        __builtin_amdgcn_sched_barrier(0);

        offR = (offR == 16384u) ? 0u : offR + 8192u;
        offW = (offW == 8192u)  ? 0u : offW + 4096u;
    }

    // Epilogue. C/D layout: col = lane&15, row = (lane>>4)*4 + reg.
    if (MODE == 0) {
        _Float16* Cp = (_Float16*)(z == 0 ? C0 : z == 1 ? C1 : C2);
        const float* bp = z == 0 ? b0 : z == 1 ? b1 : b2;
        const int ldc = (z == 2) ? 8192 : 1024;
#pragma unroll
        for (int i = 0; i < 4; ++i) {
            const int rbase = m0 + wm + i * 16 + kq * 4;
#pragma unroll
            for (int j = 0; j < 4; ++j) {
                const int gcol = n0 + wn + j * 16 + ln;
#pragma unroll
                for (int r = 0; r < 4; ++r) {
                    float vv = acc[i][j][r] + (z == 2 ? bp[rbase + r] : bp[gcol]);
                    Cp[(size_t)(rbase + r) * ldc + gcol] = (_Float16)vv;
                }
            }
        }
    } else if (MODE == 3) {
        _Float16* Ch = (_Float16*)C0;
#pragma unroll
        for (int i = 0; i < 4; ++i) {
            const int rbase = m0 + wm + i * 16 + kq * 4;
            float rs[4] = {0.f, 0.f, 0.f, 0.f};
#pragma unroll
            for (int j = 0; j < 4; ++j) {
                const int gcol = n0 + wn + j * 16 + ln;
#pragma unroll
                for (int r = 0; r < 4; ++r) {
                    float e = __expf(acc[i][j][r] * 0.03125f);
                    Ch[cbase + (size_t)(rbase + r) * 2048 + gcol] = (_Float16)e;
                    rs[r] += e;
                }
            }
#pragma unroll
            for (int r = 0; r < 4; ++r) {
                float s = rs[r];
                s += __shfl_xor(s, 1);
                s += __shfl_xor(s, 2);
                s += __shfl_xor(s, 4);
                s += __shfl_xor(s, 8);
                if (ln == 0) atomicAdd(&rowsum[rbase + r], s);
            }
        }
    } else {
        float* Cf = (float*)C0;
#pragma unroll
        for (int i = 0; i < 4; ++i) {
            const int rbase = m0 + wm + i * 16 + kq * 4;
            float inv[4];
#pragma unroll
            for (int r = 0; r < 4; ++r) inv[r] = 1.f / rowsum[rbase + r];
#pragma unroll
            for (int j = 0; j < 4; ++j) {
                const int gcol = n0 + wn + j * 16 + ln;
#pragma unroll
                for (int r = 0; r < 4; ++r)
                    Cf[cbase + (size_t)(rbase + r) * 1024 + gcol] = acc[i][j][r] * inv[r];
            }
        }
    }
}

// ---------------------------------------------------------------------------
// Prep kernel, ONE launch. grid (8192, 4), 256 threads:
//   y in {0,1,2}: f32->f16 convert of X_y (float4/thread); y==0,x<32 zeros rowsum.
//   y==3, x<3072: 32x32 transpose tile of W_{x/1024} -> f16 W^T.
// ---------------------------------------------------------------------------
__global__ __launch_bounds__(256)
void prep(const float4* __restrict__ x0, _Float16* __restrict__ y0,
          const float4* __restrict__ x1, _Float16* __restrict__ y1,
          const float4* __restrict__ x2, _Float16* __restrict__ y2,
          const float* __restrict__ W0, _Float16* __restrict__ T0,
          const float* __restrict__ W1, _Float16* __restrict__ T1,
          const float* __restrict__ W2, _Float16* __restrict__ T2,
          float* __restrict__ rowsum)
{
    if (blockIdx.y < 3) {
        const size_t i = (size_t)blockIdx.x * 256 + threadIdx.x;
        const float4* x = blockIdx.y == 0 ? x0 : blockIdx.y == 1 ? x1 : x2;
        _Float16*    yy = blockIdx.y == 0 ? y0 : blockIdx.y == 1 ? y1 : y2;
        float4 f = x[i];
        f16x4 o = { (_Float16)f.x, (_Float16)f.y, (_Float16)f.z, (_Float16)f.w };
        *(f16x4*)(yy + i * 4) = o;
        if (blockIdx.y == 0 && blockIdx.x < 32)
            rowsum[blockIdx.x * 256 + threadIdx.x] = 0.f;
        return;
    }
    if (blockIdx.x >= 3072) return;
    const int zz = blockIdx.x >> 10;          // which W
    const int tb = blockIdx.x & 1023;         // tile id: 32x32 grid of 32x32 tiles
    const float* W = zz == 0 ? W0 : zz == 1 ? W1 : W2;
    _Float16*   WT = zz == 0 ? T0 : zz == 1 ? T1 : T2;
    __shared__ float tile[32][33];
    const int bxs = (tb & 31) * 32;           // source col block
    const int bys = (tb >> 5) * 32;           // source row block
    const int tx = threadIdx.x & 31;
    const int ty = threadIdx.x >> 5;          // 0..7
#pragma unroll
    for (int i = ty; i < 32; i += 8)
        tile[i][tx] = W[(size_t)(bys + i) * 1024 + bxs + tx];
    __syncthreads();
#pragma unroll
    for (int i = ty; i < 32; i += 8)
        WT[(size_t)(bxs + i) * 1024 + bys + tx] = (_Float16)tile[tx][i];
}

// ---------------------------------------------------------------------------
// B=4, Lq=Lk=2048, D=1024.
// prep (cvt+transpose+zero) -> {q,k,vT} one dispatch -> S~=exp(qk^T/32)+rowsum
// -> out = S~@v / rowsum.
// ---------------------------------------------------------------------------
extern "C" void kernel_launch(void* const* d_in, const int* in_sizes, int n_in,
                              void* d_out, int out_size, void* d_ws, size_t ws_size,
                              hipStream_t stream)
{
    const float* Xq = (const float*)d_in[0];
    const float* Xk = (const float*)d_in[1];
    const float* Xv = (const float*)d_in[2];
    const float* Wq = (const float*)d_in[3];
    const float* bq = (const float*)d_in[4];
    const float* Wk = (const float*)d_in[5];
    const float* bk = (const float*)d_in[6];
    const float* Wv = (const float*)d_in[7];
    const float* bv = (const float*)d_in[8];
    float* out = (float*)d_out;

    const size_t XN = (size_t)8192 * 1024;
    const size_t WN = (size_t)1024 * 1024;

    _Float16* ws  = (_Float16*)d_ws;
    _Float16* Xqh = ws;
    _Float16* Xkh = Xqh + XN;
    _Float16* Xvh = Xkh + XN;
    _Float16* WqT = Xvh + XN;
    _Float16* WkT = WqT + WN;
    _Float16* WvT = WkT + WN;
    _Float16* qh  = WvT + WN;
    _Float16* kh  = qh + XN;
    _Float16* vT  = kh + XN;                     // [1024 x 8192]
    _Float16* S   = vT + XN;                     // [4 x 2048 x 2048] (holds exp)
    float* rowsum = (float*)(S + (size_t)4 * 2048 * 2048);   // [8192]

    // 1. prep: convert X to f16, transpose W to f16 W^T, zero rowsum
    {
        dim3 g(8192, 4);
        prep<<<g, 256, 0, stream>>>((const float4*)Xq, Xqh,
                                    (const float4*)Xk, Xkh,
                                    (const float4*)Xv, Xvh,
                                    Wq, WqT, Wk, WkT, Wv, WvT, rowsum);
    }

    // 2. q, k, vT projections in ONE dispatch (1536 blocks = 2.0 waves @3/CU)
    {
        dim3 g(8, 64, 3);
        gemm_core<0><<<g, 256, 0, stream>>>(
            Xqh, WqT, qh, bq,
            Xkh, WkT, kh, bk,
            WvT, Xvh, vT, bv,
            nullptr);
    }

    // 3. S~ = exp(q k^T / 32) f16 + atomic f32 row sums (1024 blocks)
    {
        dim3 g(8, 32, 4);
        gemm_core<3><<<g, 256, 0, stream>>>(
            qh, kh, S, nullptr,
            nullptr, nullptr, nullptr, nullptr,
            nullptr, nullptr, nullptr, nullptr,
            rowsum);
    }

    // 4. out = (S~ @ v) / rowsum  (512 blocks = 2/CU balanced)
    {
        dim3 g(8, 16, 4);
        gemm_core<5><<<g, 256, 0, stream>>>(
            S, vT, out, nullptr,
            nullptr, nullptr, nullptr, nullptr,
            nullptr, nullptr, nullptr, nullptr,
            rowsum);
    }
}

// Round 7
// 298.871 us; speedup vs baseline: 1.0616x; 1.0616x over previous
//
#include <hip/hip_runtime.h>

typedef _Float16 f16x8 __attribute__((ext_vector_type(8)));
typedef _Float16 f16x4 __attribute__((ext_vector_type(4)));
typedef float f32x4 __attribute__((ext_vector_type(4)));
typedef int   v4i   __attribute__((ext_vector_type(4)));

// Async global->LDS, 16B per lane. LDS dest must be wave-uniform base; HW adds lane*16.
__device__ __forceinline__ void lds_load16(const _Float16* g, _Float16* l) {
    __builtin_amdgcn_global_load_lds(
        (const __attribute__((address_space(1))) void*)g,
        (__attribute__((address_space(3))) void*)l,
        16, 0, 0);
}

// Inline-asm LDS read (byte address). Rule #18: every use fenced by
// lgkmcnt(0) + sched_barrier(0) before the consuming MFMA.
__device__ __forceinline__ f16x8 ldsr(unsigned a) {
    v4i r;
    asm volatile("ds_read_b128 %0, %1" : "=v"(r) : "v"(a));
    return __builtin_bit_cast(f16x8, r);
}
template <int OFF>
__device__ __forceinline__ f16x8 ldsrO(unsigned a) {
    v4i r;
    if constexpr (OFF == 0)
        asm volatile("ds_read_b128 %0, %1" : "=v"(r) : "v"(a));
    else
        asm volatile("ds_read_b128 %0, %1 offset:%2" : "=v"(r) : "v"(a), "i"(OFF));
    return __builtin_bit_cast(f16x8, r);
}

// ---------------------------------------------------------------------------
// MODE0 core (R6, measured 72.2us): high-TLP old-drain pipeline.
// Tile 128x128, BK=32, 256 thr = 4 waves (2x2), wave-tile 64x64, acc[4][4].
// TRIPLE-buffered LDS (48KB -> 3 blocks/CU, 12 waves/CU). Per K-step kc:
//   { ds_read frags from buf kc%3 -> stage buf (kc+2)%3 (4 gload_lds)
//     -> lgkmcnt(0) -> setprio(1) 16 MFMA setprio(0)
//     -> vmcnt(4) [drains stage kc+1, issued a FULL ITERATION ago => ~free;
//        keeps kc+2's 4 loads in flight] -> s_barrier }.
// Swizzle (both-sides, rule #21): LDS[row][slot] = G[row][slot^((row>>1)&3)].
// Triple projection, z in {0,1,2}:
//   z=0: q = Xqh@WqT^T + bq[n]   z=1: k = Xkh@WkT^T + bk[n]   (ldc=1024)
//   z=2: vT = WvT@Xvh^T + bv[m]  (ldc=8192)
// grid (8,64,3) = 1536 blocks = 2.0 exact machine-waves at 3/CU.
// ---------------------------------------------------------------------------
__global__ __launch_bounds__(256, 3)
void gemm_proj(const _Float16* A0, const _Float16* B0, void* C0, const float* b0,
               const _Float16* A1, const _Float16* B1, void* C1, const float* b1,
               const _Float16* A2, const _Float16* B2, void* C2, const float* b2)
{
    constexpr int K = 1024, LDA = 1024, LDB = 1024, NT = K / 32;

    __shared__ __align__(16) _Float16 As[3][128 * 32];
    __shared__ __align__(16) _Float16 Bs[3][128 * 32];

    const int z  = blockIdx.z;
    const int bx = blockIdx.x, by = blockIdx.y;
    const int t    = threadIdx.x;
    const int w    = t >> 6;
    const int lane = t & 63;
    const int ln   = lane & 15;
    const int kq   = lane >> 4;
    const int wm   = (w & 1) * 64;
    const int wn   = (w >> 1) * 64;

    const _Float16* A = z == 0 ? A0 : z == 1 ? A1 : A2;
    const _Float16* B = z == 0 ? B0 : z == 1 ? B1 : B2;
    int m0, n0;
    if (z == 2) { m0 = (by & 7) * 128; n0 = (bx * 8 + (by >> 3)) * 128; }
    else        { m0 = (bx * 8 + (by >> 3)) * 128; n0 = (by & 7) * 128; }

    // staging: thread t covers rows r4=t>>2 and r4+64; chunk (t&3)^((r4>>1)&3).
    const int r4 = t >> 2;
    const int sc = ((t & 3) ^ ((t >> 3) & 3)) * 8;
    const _Float16* gA = A + (size_t)(m0 + r4) * LDA + sc;
    const _Float16* gB = B + (size_t)(n0 + r4) * LDB + sc;
    _Float16* const lA = &As[0][0] + w * 512;
    _Float16* const lB = &Bs[0][0] + w * 512;

    auto stage = [&](unsigned bufE, int kt) {
        lds_load16(gA + kt * 32,                     lA + bufE);
        lds_load16(gA + (size_t)64 * LDA + kt * 32,  lA + bufE + 2048);
        lds_load16(gB + kt * 32,                     lB + bufE);
        lds_load16(gB + (size_t)64 * LDB + kt * 32,  lB + bufE + 2048);
    };

    const int sk = (kq ^ ((ln >> 1) & 3)) * 16;
    const unsigned uA0 = (unsigned)(uintptr_t)(__attribute__((address_space(3))) _Float16*)&As[0][0];
    const unsigned uB0 = (unsigned)(uintptr_t)(__attribute__((address_space(3))) _Float16*)&Bs[0][0];
    const unsigned vAbase = uA0 + (wm + ln) * 64 + sk;
    const unsigned vBbase = uB0 + (wn + ln) * 64 + sk;

    f32x4 acc[4][4] = {};

    stage(0, 0);
    stage(4096, 1);
    asm volatile("s_waitcnt vmcnt(4)" ::: "memory");
    __builtin_amdgcn_s_barrier();
    __builtin_amdgcn_sched_barrier(0);

    unsigned offR = 0;        // read-buf byte offset
    unsigned offW = 8192;     // stage-buf elem offset

    for (int kc = 0; kc < NT; ++kc) {
        const unsigned aA = vAbase + offR;
        const unsigned aB = vBbase + offR;
        f16x8 af[4], bf[4];
        af[0] = ldsrO<0>(aA);    af[1] = ldsrO<1024>(aA);
        af[2] = ldsrO<2048>(aA); af[3] = ldsrO<3072>(aA);
        bf[0] = ldsrO<0>(aB);    bf[1] = ldsrO<1024>(aB);
        bf[2] = ldsrO<2048>(aB); bf[3] = ldsrO<3072>(aB);

        const bool pf = (kc + 2 < NT);
        if (pf) stage(offW, kc + 2);

        asm volatile("s_waitcnt lgkmcnt(0)" ::: "memory");
        __builtin_amdgcn_sched_barrier(0);
        __builtin_amdgcn_s_setprio(1);
#pragma unroll
        for (int i = 0; i < 4; ++i)
#pragma unroll
            for (int j = 0; j < 4; ++j)
                acc[i][j] = __builtin_amdgcn_mfma_f32_16x16x32_f16(af[i], bf[j], acc[i][j], 0, 0, 0);
        __builtin_amdgcn_s_setprio(0);
        __builtin_amdgcn_sched_barrier(0);

        if (pf) asm volatile("s_waitcnt vmcnt(4)" ::: "memory");
        else    asm volatile("s_waitcnt vmcnt(0)" ::: "memory");
        __builtin_amdgcn_s_barrier();
        __builtin_amdgcn_sched_barrier(0);

        offR = (offR == 16384u) ? 0u : offR + 8192u;
        offW = (offW == 8192u)  ? 0u : offW + 4096u;
    }

    // Epilogue. C/D layout: col = lane&15, row = (lane>>4)*4 + reg.
    _Float16* Cp = (_Float16*)(z == 0 ? C0 : z == 1 ? C1 : C2);
    const float* bp = z == 0 ? b0 : z == 1 ? b1 : b2;
    const int ldc = (z == 2) ? 8192 : 1024;
#pragma unroll
    for (int i = 0; i < 4; ++i) {
        const int rbase = m0 + wm + i * 16 + kq * 4;
#pragma unroll
        for (int j = 0; j < 4; ++j) {
            const int gcol = n0 + wn + j * 16 + ln;
#pragma unroll
            for (int r = 0; r < 4; ++r) {
                float vv = acc[i][j][r] + (z == 2 ? bp[rbase + r] : bp[gcol]);
                Cp[(size_t)(rbase + r) * ldc + gcol] = (_Float16)vv;
            }
        }
    }
}

// ---------------------------------------------------------------------------
// MODE3/MODE5 core (R5, best measured combined): 8-phase counted-vmcnt with
// fine per-phase staging. Tile BMx256 (BM=256 M3 / 128 M5), BK=64, 512 thr =
// 8 waves (2M x 4N), wave-tile (BM/2)x64, acc[MI][4]. Per K-tile kc (buf
// b=kc&1), 4 phases: { ds_reads for THIS phase -> stage 2-3 gload_lds for
// kc+2 into regions freed by the PREVIOUS phase -> s_barrier -> lgkmcnt(0)
// -> setprio(1) MFMA quadrant (kh-outer) setprio(0) -> s_barrier }.
// Drain: vmcnt(8) (6 for M5) at end of ph3 -- never vmcnt(0) steady-state.
// Swizzle: LDS[row][slot16B] = G[row][slot ^ (row&7)], both sides.
// MODE 3: S~ = exp((q k^T)/32) f16 + atomic f32 row sums; grid (8,8,4).
// MODE 5: out = (S~ @ v) * (1/rowsum[row]) f32; grid (8,16,2).
// ---------------------------------------------------------------------------
template <int MODE>
__global__ __launch_bounds__(512, 2)
void gemm_attn(const _Float16* A0, const _Float16* B0, void* C0, float* rowsum)
{
    constexpr int BM  = (MODE == 5) ? 128 : 256;
    constexpr int K   = (MODE == 5) ? 2048 : 1024;
    constexpr int LDA = (MODE == 5) ? 2048 : 1024;
    constexpr int LDB = (MODE == 5) ? 8192 : 1024;
    constexpr int NT  = K / 64;
    constexpr int MI  = BM / 32;
    constexpr int MH  = MI / 2;
    constexpr int LA  = BM / 64;

    __shared__ __align__(16) _Float16 As[2][BM * 64];
    __shared__ __align__(16) _Float16 Bs[2][256 * 64];

    const int bx = blockIdx.x, by = blockIdx.y;
    const int t    = threadIdx.x;
    const int w    = t >> 6;
    const int lane = t & 63;
    const int ln   = lane & 15;
    const int kq   = lane >> 4;
    const int wm   = (w >> 2) * (BM / 2);
    const int wn   = (w & 3) * 64;

    const _Float16* A;
    const _Float16* B;
    size_t cbase = 0;
    int m0, n0, z;

    if (MODE == 3) {
        // grid (8,8,4); XCD = bx. 2x4 super-tile per XCD.
        z = blockIdx.z;
        A = A0 + (size_t)z * 2048 * 1024;      // q slice
        B = B0 + (size_t)z * 2048 * 1024;      // k slice
        cbase = (size_t)z * 2048 * 2048;
        rowsum += z * 2048;
        m0 = ((bx & 3) * 2 + (by >> 2)) * 256;
        n0 = ((bx >> 2) * 4 + (by & 3)) * 256;
    } else {
        // grid (8,16,2); XCD = bx: 256-col vT slice x 2 z L2-resident.
        z = (blockIdx.z << 1) | (bx >> 2);
        A = A0 + (size_t)z * 2048 * 2048;      // S~ slice
        B = B0 + (size_t)z * 2048;             // vT col offset
        cbase = (size_t)z * 2048 * 1024;
        rowsum += z * 2048;
        m0 = by * 128;
        n0 = (bx & 3) * 256;
    }

    // staging: thread t: row r6 = t>>3 per 64-row block; chunk (t&7)^(r6&7).
    const int r6 = t >> 3;
    const int cw = ((t & 7) ^ (r6 & 7)) * 8;
    const _Float16* gA = A + (size_t)(m0 + r6) * LDA + cw;
    const _Float16* gB = B + (size_t)(n0 + r6) * LDB + cw;

    auto stA = [&](int b, int kt, int s) {
        lds_load16(gA + (size_t)(s * 64) * LDA + kt * 64, As[b] + s * 4096 + w * 512);
    };
    auto stB = [&](int b, int kt, int s) {
        lds_load16(gB + (size_t)(s * 64) * LDB + kt * 64, Bs[b] + s * 4096 + w * 512);
    };

    const int xr  = ln & 7;
    const int sk0 = ((0 + kq) ^ xr) * 8;
    const int sk1 = ((4 + kq) ^ xr) * 8;
    const int ra  = (wm + ln) * 64;
    const int rb  = (wn + ln) * 64;

    const unsigned uA0 = (unsigned)(uintptr_t)(__attribute__((address_space(3))) _Float16*)&As[0][0];
    const unsigned uA1 = (unsigned)(uintptr_t)(__attribute__((address_space(3))) _Float16*)&As[1][0];
    const unsigned uB0 = (unsigned)(uintptr_t)(__attribute__((address_space(3))) _Float16*)&Bs[0][0];
    const unsigned uB1 = (unsigned)(uintptr_t)(__attribute__((address_space(3))) _Float16*)&Bs[1][0];
    const unsigned aA[2][2] = { { uA0 + 2u * (ra + sk0), uA0 + 2u * (ra + sk1) },
                                { uA1 + 2u * (ra + sk0), uA1 + 2u * (ra + sk1) } };
    const unsigned aB[2][2] = { { uB0 + 2u * (rb + sk0), uB0 + 2u * (rb + sk1) },
                                { uB1 + 2u * (rb + sk0), uB1 + 2u * (rb + sk1) } };

    f16x8 af[MH][2], bf[4][2];
    f32x4 acc[MI][4] = {};

    // prologue
    {
#pragma unroll
        for (int s = 0; s < LA; ++s) stA(0, 0, s);
#pragma unroll
        for (int s = 0; s < 4; ++s)  stB(0, 0, s);
#pragma unroll
        for (int s = 0; s < LA; ++s) stA(1, 1, s);
#pragma unroll
        for (int s = 0; s < 4; ++s)  stB(1, 1, s);
    }
    if constexpr (MODE == 5) asm volatile("s_waitcnt vmcnt(6)" ::: "memory");
    else                     asm volatile("s_waitcnt vmcnt(8)" ::: "memory");
    __builtin_amdgcn_s_barrier();
    __builtin_amdgcn_sched_barrier(0);

#pragma unroll 2
    for (int kc = 0; kc < NT; ++kc) {
        const int  b  = kc & 1;
        const bool pf = (kc + 2 < NT);

        // phase 0: reads af-lo + bf[0,1]; MFMA (i-lo, j0-1)
#pragma unroll
        for (int i = 0; i < MH; ++i) {
            af[i][0] = ldsr(aA[b][0] + i * 2048);
            af[i][1] = ldsr(aA[b][1] + i * 2048);
        }
#pragma unroll
        for (int j = 0; j < 2; ++j) {
            bf[j][0] = ldsr(aB[b][0] + j * 2048);
            bf[j][1] = ldsr(aB[b][1] + j * 2048);
        }
        __builtin_amdgcn_s_barrier();
        asm volatile("s_waitcnt lgkmcnt(0)" ::: "memory");
        __builtin_amdgcn_sched_barrier(0);
        __builtin_amdgcn_s_setprio(1);
#pragma unroll
        for (int kh = 0; kh < 2; ++kh)
#pragma unroll
            for (int i = 0; i < MH; ++i)
#pragma unroll
                for (int j = 0; j < 2; ++j)
                    acc[i][j] = __builtin_amdgcn_mfma_f32_16x16x32_f16(af[i][kh], bf[j][kh], acc[i][j], 0, 0, 0);
        __builtin_amdgcn_s_setprio(0);
        __builtin_amdgcn_s_barrier();
        __builtin_amdgcn_sched_barrier(0);

        // phase 1: reads bf[2,3]; stage A s0,s2; MFMA (i-lo, j2-3)
#pragma unroll
        for (int j = 2; j < 4; ++j) {
            bf[j][0] = ldsr(aB[b][0] + j * 2048);
            bf[j][1] = ldsr(aB[b][1] + j * 2048);
        }
        if constexpr (LA == 4) {
            if (pf) { stA(b, kc + 2, 0); stA(b, kc + 2, 2); }
        }
        __builtin_amdgcn_s_barrier();
        asm volatile("s_waitcnt lgkmcnt(0)" ::: "memory");
        __builtin_amdgcn_sched_barrier(0);
        __builtin_amdgcn_s_setprio(1);
#pragma unroll
        for (int kh = 0; kh < 2; ++kh)
#pragma unroll
            for (int i = 0; i < MH; ++i)
#pragma unroll
                for (int j = 2; j < 4; ++j)
                    acc[i][j] = __builtin_amdgcn_mfma_f32_16x16x32_f16(af[i][kh], bf[j][kh], acc[i][j], 0, 0, 0);
        __builtin_amdgcn_s_setprio(0);
        __builtin_amdgcn_s_barrier();
        __builtin_amdgcn_sched_barrier(0);

        // phase 2: reads af-hi; stage B s0-s2; MFMA (i-hi, j0-1)
#pragma unroll
        for (int i = 0; i < MH; ++i) {
            af[i][0] = ldsr(aA[b][0] + (i + MH) * 2048);
            af[i][1] = ldsr(aA[b][1] + (i + MH) * 2048);
        }
        if (pf) { stB(b, kc + 2, 0); stB(b, kc + 2, 1); stB(b, kc + 2, 2); }
        __builtin_amdgcn_s_barrier();
        asm volatile("s_waitcnt lgkmcnt(0)" ::: "memory");
        __builtin_amdgcn_sched_barrier(0);
        __builtin_amdgcn_s_setprio(1);
#pragma unroll
        for (int kh = 0; kh < 2; ++kh)
#pragma unroll
            for (int i = 0; i < MH; ++i)
#pragma unroll
                for (int j = 0; j < 2; ++j)
                    acc[i + MH][j] = __builtin_amdgcn_mfma_f32_16x16x32_f16(af[i][kh], bf[j][kh], acc[i + MH][j], 0, 0, 0);
        __builtin_amdgcn_s_setprio(0);
        __builtin_amdgcn_s_barrier();
        __builtin_amdgcn_sched_barrier(0);

        // phase 3: stage B s3 + A remainder; counted drain; MFMA (i-hi, j2-3)
        if (pf) {
            stB(b, kc + 2, 3);
            if constexpr (LA == 4) { stA(b, kc + 2, 1); stA(b, kc + 2, 3); }
            else                   { stA(b, kc + 2, 0); stA(b, kc + 2, 1); }
            if constexpr (MODE == 5) asm volatile("s_waitcnt vmcnt(6)" ::: "memory");
            else                     asm volatile("s_waitcnt vmcnt(8)" ::: "memory");
        } else if (kc + 1 < NT) {
            asm volatile("s_waitcnt vmcnt(0)" ::: "memory");
        }
        __builtin_amdgcn_s_barrier();
        __builtin_amdgcn_sched_barrier(0);
        __builtin_amdgcn_s_setprio(1);
#pragma unroll
        for (int kh = 0; kh < 2; ++kh)
#pragma unroll
            for (int i = 0; i < MH; ++i)
#pragma unroll
                for (int j = 2; j < 4; ++j)
                    acc[i + MH][j] = __builtin_amdgcn_mfma_f32_16x16x32_f16(af[i][kh], bf[j][kh], acc[i + MH][j], 0, 0, 0);
        __builtin_amdgcn_s_setprio(0);
        __builtin_amdgcn_s_barrier();
        __builtin_amdgcn_sched_barrier(0);
    }

    // Epilogue. C/D layout: col = lane&15, row = (lane>>4)*4 + reg.
    if (MODE == 3) {
        _Float16* Ch = (_Float16*)C0;
#pragma unroll
        for (int i = 0; i < MI; ++i) {
            const int rbase = m0 + wm + i * 16 + kq * 4;
            float rs[4] = {0.f, 0.f, 0.f, 0.f};
#pragma unroll
            for (int j = 0; j < 4; ++j) {
                const int gcol = n0 + wn + j * 16 + ln;
#pragma unroll
                for (int r = 0; r < 4; ++r) {
                    float e = __expf(acc[i][j][r] * 0.03125f);
                    Ch[cbase + (size_t)(rbase + r) * 2048 + gcol] = (_Float16)e;
                    rs[r] += e;
                }
            }
#pragma unroll
            for (int r = 0; r < 4; ++r) {
                float s = rs[r];
                s += __shfl_xor(s, 1);
                s += __shfl_xor(s, 2);
                s += __shfl_xor(s, 4);
                s += __shfl_xor(s, 8);
                if (ln == 0) atomicAdd(&rowsum[rbase + r], s);
            }
        }
    } else {
        float* Cf = (float*)C0;
#pragma unroll
        for (int i = 0; i < MI; ++i) {
            const int rbase = m0 + wm + i * 16 + kq * 4;
            float inv[4];
#pragma unroll
            for (int r = 0; r < 4; ++r) inv[r] = 1.f / rowsum[rbase + r];
#pragma unroll
            for (int j = 0; j < 4; ++j) {
                const int gcol = n0 + wn + j * 16 + ln;
#pragma unroll
                for (int r = 0; r < 4; ++r)
                    Cf[cbase + (size_t)(rbase + r) * 1024 + gcol] = acc[i][j][r] * inv[r];
            }
        }
    }
}

// ---------------------------------------------------------------------------
// Prep kernel, ONE launch. grid (8192, 4), 256 threads:
//   y in {0,1,2}: f32->f16 convert of X_y (float4/thread); y==0,x<32 zeros rowsum.
//   y==3, x<3072: 32x32 transpose tile of W_{x/1024} -> f16 W^T.
// ---------------------------------------------------------------------------
__global__ __launch_bounds__(256)
void prep(const float4* __restrict__ x0, _Float16* __restrict__ y0,
          const float4* __restrict__ x1, _Float16* __restrict__ y1,
          const float4* __restrict__ x2, _Float16* __restrict__ y2,
          const float* __restrict__ W0, _Float16* __restrict__ T0,
          const float* __restrict__ W1, _Float16* __restrict__ T1,
          const float* __restrict__ W2, _Float16* __restrict__ T2,
          float* __restrict__ rowsum)
{
    if (blockIdx.y < 3) {
        const size_t i = (size_t)blockIdx.x * 256 + threadIdx.x;
        const float4* x = blockIdx.y == 0 ? x0 : blockIdx.y == 1 ? x1 : x2;
        _Float16*    yy = blockIdx.y == 0 ? y0 : blockIdx.y == 1 ? y1 : y2;
        float4 f = x[i];
        f16x4 o = { (_Float16)f.x, (_Float16)f.y, (_Float16)f.z, (_Float16)f.w };
        *(f16x4*)(yy + i * 4) = o;
        if (blockIdx.y == 0 && blockIdx.x < 32)
            rowsum[blockIdx.x * 256 + threadIdx.x] = 0.f;
        return;
    }
    if (blockIdx.x >= 3072) return;
    const int zz = blockIdx.x >> 10;          // which W
    const int tb = blockIdx.x & 1023;         // tile id: 32x32 grid of 32x32 tiles
    const float* W = zz == 0 ? W0 : zz == 1 ? W1 : W2;
    _Float16*   WT = zz == 0 ? T0 : zz == 1 ? T1 : T2;
    __shared__ float tile[32][33];
    const int bxs = (tb & 31) * 32;           // source col block
    const int bys = (tb >> 5) * 32;           // source row block
    const int tx = threadIdx.x & 31;
    const int ty = threadIdx.x >> 5;          // 0..7
#pragma unroll
    for (int i = ty; i < 32; i += 8)
        tile[i][tx] = W[(size_t)(bys + i) * 1024 + bxs + tx];
    __syncthreads();
#pragma unroll
    for (int i = ty; i < 32; i += 8)
        WT[(size_t)(bxs + i) * 1024 + bys + tx] = (_Float16)tile[tx][i];
}

// ---------------------------------------------------------------------------
// B=4, Lq=Lk=2048, D=1024.
// prep (cvt+transpose+zero) -> {q,k,vT} one dispatch -> S~=exp(qk^T/32)+rowsum
// -> out = S~@v / rowsum.
// ---------------------------------------------------------------------------
extern "C" void kernel_launch(void* const* d_in, const int* in_sizes, int n_in,
                              void* d_out, int out_size, void* d_ws, size_t ws_size,
                              hipStream_t stream)
{
    const float* Xq = (const float*)d_in[0];
    const float* Xk = (const float*)d_in[1];
    const float* Xv = (const float*)d_in[2];
    const float* Wq = (const float*)d_in[3];
    const float* bq = (const float*)d_in[4];
    const float* Wk = (const float*)d_in[5];
    const float* bk = (const float*)d_in[6];
    const float* Wv = (const float*)d_in[7];
    const float* bv = (const float*)d_in[8];
    float* out = (float*)d_out;

    const size_t XN = (size_t)8192 * 1024;
    const size_t WN = (size_t)1024 * 1024;

    _Float16* ws  = (_Float16*)d_ws;
    _Float16* Xqh = ws;
    _Float16* Xkh = Xqh + XN;
    _Float16* Xvh = Xkh + XN;
    _Float16* WqT = Xvh + XN;
    _Float16* WkT = WqT + WN;
    _Float16* WvT = WkT + WN;
    _Float16* qh  = WvT + WN;
    _Float16* kh  = qh + XN;
    _Float16* vT  = kh + XN;                     // [1024 x 8192]
    _Float16* S   = vT + XN;                     // [4 x 2048 x 2048] (holds exp)
    float* rowsum = (float*)(S + (size_t)4 * 2048 * 2048);   // [8192]

    // 1. prep: convert X to f16, transpose W to f16 W^T, zero rowsum
    {
        dim3 g(8192, 4);
        prep<<<g, 256, 0, stream>>>((const float4*)Xq, Xqh,
                                    (const float4*)Xk, Xkh,
                                    (const float4*)Xv, Xvh,
                                    Wq, WqT, Wk, WkT, Wv, WvT, rowsum);
    }

    // 2. q, k, vT projections in ONE dispatch (1536 blocks = 2.0 waves @3/CU)
    {
        dim3 g(8, 64, 3);
        gemm_proj<<<g, 256, 0, stream>>>(
            Xqh, WqT, qh, bq,
            Xkh, WkT, kh, bk,
            WvT, Xvh, vT, bv);
    }

    // 3. S~ = exp(q k^T / 32) f16 + atomic f32 row sums (256 blocks, 1/CU)
    {
        dim3 g(8, 8, 4);
        gemm_attn<3><<<g, 512, 0, stream>>>(qh, kh, S, rowsum);
    }

    // 4. out = (S~ @ v) / rowsum  (128x256 tiles, 256 blocks)
    {
        dim3 g(8, 16, 2);
        gemm_attn<5><<<g, 512, 0, stream>>>(S, vT, out, rowsum);
    }
}